// Round 6
// baseline (326.046 us; speedup 1.0000x reference)
//
#include <hip/hip_runtime.h>
#include <cstddef>
#include <cstdint>

// Problem constants (B,T,D fixed by the reference).
#define B_ 8
#define T_ 4096
#define D_ 1024
#define M_ (B_*T_)        // 32768 rows
#define K_ 1024
#define NC 32             // scan chunks per sequence
#define CL 128            // steps per chunk

// GEMM tile config: 256x128 output tile, dual-B (r and i), BK=32, 8 waves,
// quad-buffered LDS, depth-3 prefetch.
#define BM 256
#define BN 128
#define BK 32
#define KCHUNKS 32

typedef __bf16 bf16x8 __attribute__((ext_vector_type(8)));
typedef float  f32x4  __attribute__((ext_vector_type(4)));

__device__ __forceinline__ void gload_lds16(const __bf16* g, __bf16* l) {
    __builtin_amdgcn_global_load_lds(
        (const __attribute__((address_space(1))) void*)g,
        (__attribute__((address_space(3))) void*)l, 16, 0, 0);
}

__device__ __forceinline__ float bfbits2f(uint32_t hi16_as_low) {
    return __builtin_bit_cast(float, hi16_as_low);
}

// ---------------------------------------------------------------------------
// cvt_swz: fp32 [rows][1024] -> bf16, reorganized into 32 k-chunks of 32 cols,
// each row 64B, XOR-swizzled within the row: byte ^= (row&3)<<4 (involution on
// 16B units). Inverse-swizzled source so linear global_load_lds staging lands
// the swizzle in LDS and ds_read applies the same XOR (G21).
// ---------------------------------------------------------------------------
__global__ __launch_bounds__(256) void cvt_swz(const float* __restrict__ src,
                                               __bf16* __restrict__ dst, int rows)
{
    const int g  = blockIdx.x * 256 + threadIdx.x;   // rows*128 threads
    const int r  = g >> 7;
    const int k0 = (g & 127) << 3;                   // 8 elems per thread
    const int kc = k0 >> 5;                          // 32-col chunks
    const int jj = k0 & 31;                          // 0,8,16,24
    const float4 v0 = *reinterpret_cast<const float4*>(src + (size_t)r * 1024 + k0);
    const float4 v1 = *reinterpret_cast<const float4*>(src + (size_t)r * 1024 + k0 + 4);
    bf16x8 s;
    s[0]=(__bf16)v0.x; s[1]=(__bf16)v0.y; s[2]=(__bf16)v0.z; s[3]=(__bf16)v0.w;
    s[4]=(__bf16)v1.x; s[5]=(__bf16)v1.y; s[6]=(__bf16)v1.z; s[7]=(__bf16)v1.w;
    const uint32_t inrow = (uint32_t)(r * 64 + ((jj << 1) ^ ((r & 3) << 4)));
    const size_t byteoff = (size_t)kc * ((size_t)rows * 64) + inrow;
    *reinterpret_cast<bf16x8*>(reinterpret_cast<char*>(dst) + byteoff) = s;
}

// ---------------------------------------------------------------------------
// K1: fused dual-GEMM + slim gate epilogue. Quad-buffered, depth-3 prefetch,
// one barrier per K-chunk, counted vmcnt(8) (never 0 mid-loop), hoisted
// ds_read offsets. zr = x@Wa^T+ba, zi = x@Wx^T+bx; r=sig(zr), i=sig(zi);
// e = 8*r*log2(sig(lambda)); stores packed dword {lo: bf16(e), hi: bf16(i*x)}.
// ---------------------------------------------------------------------------
__global__ __launch_bounds__(512, 1) void rg_gemm_gate(
    const __bf16* __restrict__ Xsw, const __bf16* __restrict__ Wasw,
    const __bf16* __restrict__ Wxsw, const float* __restrict__ Ba,
    const float* __restrict__ Bx, const float* __restrict__ LL,
    uint32_t* __restrict__ EIX)
{
    __shared__ __bf16 Al [4][BM * BK];   // 4 x 16 KiB = 64 KiB
    __shared__ __bf16 Brs[4][BN * BK];   // 4 x  8 KiB = 32 KiB
    __shared__ __bf16 Bis[4][BN * BK];   // 32 KiB   -> 128 KiB total

    const int tid  = threadIdx.x;
    const int lane = tid & 63;
    const int w    = tid >> 6;           // 8 waves: 4M x 2N
    const int wr   = (w >> 1) * 64;
    const int wc   = (w & 1) * 64;

    // XCD swizzle (1024 blocks, %8==0): n-tile fastest within each XCD.
    const int bid  = blockIdx.x;
    const int wgid = (bid & 7) * 128 + (bid >> 3);
    const int n0   = (wgid & 7) << 7;    // 8 n-tiles
    const int m0   = (wgid >> 3) << 8;   // 128 m-tiles

    const int lrow = lane & 15;

    // ---- hoisted ds_read byte offsets (loop-invariant; buf base added/chunk)
    uint32_t offA[4], offB[4];
    #pragma unroll
    for (int mi = 0; mi < 4; ++mi) {
        const int ra = wr + mi * 16 + lrow;
        offA[mi] = (uint32_t)(ra * 64) + ((uint32_t)((lane >> 4) << 4)
                                          ^ (uint32_t)((ra & 3) << 4));
    }
    #pragma unroll
    for (int ni = 0; ni < 4; ++ni) {
        const int rb = wc + ni * 16 + lrow;
        offB[ni] = (uint32_t)(rb * 64) + ((uint32_t)((lane >> 4) << 4)
                                          ^ (uint32_t)((rb & 3) << 4));
    }

    // ---- hoisted stage cursors (per-chunk advance is a shift-mul) --------
    // Per chunk a wave issues 4 gl_lds (1 KiB each): A pieces {w, w+8}, Br
    // piece w, Bi piece w. Piece p covers rows 16p..16p+15 (linear 64B rows).
    const char* srcA  = reinterpret_cast<const char*>(Xsw)
                      + (size_t)m0 * 64 + w * 1024 + lane * 16;
    const char* srcBr = reinterpret_cast<const char*>(Wasw)
                      + (size_t)n0 * 64 + w * 1024 + lane * 16;
    const char* srcBi = reinterpret_cast<const char*>(Wxsw)
                      + (size_t)n0 * 64 + w * 1024 + lane * 16;
    const size_t strA = (size_t)M_ * 64;     // 2 MiB (shift)
    const size_t strB = (size_t)1024 * 64;   // 64 KiB (shift)

    auto STAGE = [&](int kc) {
        const int buf = kc & 3;
        const char* sA = srcA + (size_t)kc * strA;
        gload_lds16((const __bf16*)sA,          &Al[buf][w * 512]);
        gload_lds16((const __bf16*)(sA + 8192), &Al[buf][(w + 8) * 512]);
        gload_lds16((const __bf16*)(srcBr + (size_t)kc * strB), &Brs[buf][w * 512]);
        gload_lds16((const __bf16*)(srcBi + (size_t)kc * strB), &Bis[buf][w * 512]);
    };

    f32x4 accr[4][4] = {};
    f32x4 acci[4][4] = {};

    // Prologue: 3 stages in flight (12 outstanding loads per wave).
    STAGE(0); STAGE(1); STAGE(2);

    for (int kc = 0; kc < KCHUNKS; ++kc) {
        // Drain stage kc; keep kc+1, kc+2 (8 loads) in flight. Tail shrinks.
        if (kc < KCHUNKS - 2)      asm volatile("s_waitcnt vmcnt(8)" ::: "memory");
        else if (kc == KCHUNKS - 2) asm volatile("s_waitcnt vmcnt(4)" ::: "memory");
        else                        asm volatile("s_waitcnt vmcnt(0)" ::: "memory");
        __builtin_amdgcn_s_barrier();   // publish stage kc; all reads of the
                                        // buf that STAGE(kc+3) targets retired
        if (kc < KCHUNKS - 3) STAGE(kc + 3);

        const char* Ab = reinterpret_cast<const char*>(&Al [kc & 3][0]);
        const char* Rb = reinterpret_cast<const char*>(&Brs[kc & 3][0]);
        const char* Ib = reinterpret_cast<const char*>(&Bis[kc & 3][0]);

        bf16x8 af[4], brf[4], bif[4];
        #pragma unroll
        for (int mi = 0; mi < 4; ++mi)
            af[mi] = *reinterpret_cast<const bf16x8*>(Ab + offA[mi]);
        #pragma unroll
        for (int ni = 0; ni < 4; ++ni) {
            brf[ni] = *reinterpret_cast<const bf16x8*>(Rb + offB[ni]);
            bif[ni] = *reinterpret_cast<const bf16x8*>(Ib + offB[ni]);
        }
        #pragma unroll
        for (int mi = 0; mi < 4; ++mi) {
            #pragma unroll
            for (int ni = 0; ni < 4; ++ni) {
                accr[mi][ni] = __builtin_amdgcn_mfma_f32_16x16x32_bf16(
                    af[mi], brf[ni], accr[mi][ni], 0, 0, 0);
                acci[mi][ni] = __builtin_amdgcn_mfma_f32_16x16x32_bf16(
                    af[mi], bif[ni], acci[mi][ni], 0, 0, 0);
            }
        }
    }

    // ---- epilogue: C/D layout col = lane&15, row = (lane>>4)*4 + j ----
    const int rbase = m0 + wr + ((lane >> 4) << 2);
    const int cbase = n0 + wc + lrow;
    #pragma unroll
    for (int ni = 0; ni < 4; ++ni) {
        const int col = cbase + ni * 16;
        const float lam = LL[col];
        const float l2s = -log2f(1.0f + __expf(-lam));  // log2(sigmoid(lambda))
        const float bav = Ba[col];
        const float bxv = Bx[col];
        const int   kcx = col >> 5;
        const uint32_t colb = (uint32_t)((col & 31) << 1);
        const char* xbase = reinterpret_cast<const char*>(Xsw)
                          + (size_t)kcx * ((size_t)M_ * 64);
        #pragma unroll
        for (int mi = 0; mi < 4; ++mi) {
            #pragma unroll
            for (int j = 0; j < 4; ++j) {
                const int row = rbase + mi * 16 + j;
                const float zr = accr[mi][ni][j] + bav;
                const float zi = acci[mi][ni][j] + bxv;
                const float rv = 1.0f / (1.0f + __expf(-zr));
                const float iv = 1.0f / (1.0f + __expf(-zi));
                const float ee = 8.0f * rv * l2s;       // log2(a)
                const uint32_t inrow = (uint32_t)(row * 64)
                                     + (colb ^ (uint32_t)((row & 3) << 4));
                const uint16_t xb = *reinterpret_cast<const uint16_t*>(xbase + inrow);
                const float xv  = bfbits2f((uint32_t)xb << 16);
                const float ixv = iv * xv;
                const uint16_t ebits  = __builtin_bit_cast(uint16_t, (__bf16)ee);
                const uint16_t ixbits = __builtin_bit_cast(uint16_t, (__bf16)ixv);
                EIX[(size_t)row * D_ + col] = (uint32_t)ebits | ((uint32_t)ixbits << 16);
            }
        }
    }
}

// ---------------------------------------------------------------------------
// K2: per-chunk summaries: P = prod a = 2^(sum e), hend = local scan from 0.
// ---------------------------------------------------------------------------
__global__ __launch_bounds__(256) void rg_scan_chunks(
    const uint32_t* __restrict__ EIX, float* __restrict__ P, float* __restrict__ HE)
{
    const int g = blockIdx.x * 256 + threadIdx.x;   // < B*NC*D = 262144
    const int d = g & (D_ - 1);
    const int c = (g >> 10) & (NC - 1);
    const int b = g >> 15;
    const size_t base = ((size_t)(b * T_ + c * CL)) * D_ + d;

    float h = 0.0f;
    float se = 0.0f;
    #pragma unroll 8
    for (int t = 0; t < CL; ++t) {
        const uint32_t u = EIX[base + (size_t)t * D_];
        const float e  = bfbits2f(u << 16);
        const float ix = bfbits2f(u & 0xffff0000u);
        const float a  = exp2f(e);
        const float gate = sqrtf(fmaxf((1.0f - a) * (1.0f + a), 1e-6f));
        h = fmaf(a, h, gate * ix);
        se += e;
    }
    const int sidx = (b * NC + c) * D_ + d;
    P[sidx]  = exp2f(se);
    HE[sidx] = h;
}

// ---------------------------------------------------------------------------
// K3: sequential combine over NC chunks per (b,d); seeds with h0.
// ---------------------------------------------------------------------------
__global__ __launch_bounds__(256) void rg_combine(
    const float* __restrict__ P, const float* __restrict__ HE,
    const float* __restrict__ H0, float* __restrict__ CI,
    float* __restrict__ HF)
{
    const int g = blockIdx.x * 256 + threadIdx.x;   // < B*D = 8192
    const int d = g & (D_ - 1);
    const int b = g >> 10;
    float carry = H0[g];
    #pragma unroll
    for (int c = 0; c < NC; ++c) {
        const int sidx = (b * NC + c) * D_ + d;
        CI[sidx] = carry;
        carry = fmaf(P[sidx], carry, HE[sidx]);
    }
    HF[g] = carry;
}

// ---------------------------------------------------------------------------
// K4: final intra-chunk scan with correct carry; writes h_t to OUT (write-only).
// ---------------------------------------------------------------------------
__global__ __launch_bounds__(256) void rg_scan_final(
    const uint32_t* __restrict__ EIX, const float* __restrict__ CI,
    float* __restrict__ OUT)
{
    const int g = blockIdx.x * 256 + threadIdx.x;   // < B*NC*D
    const int d = g & (D_ - 1);
    const int c = (g >> 10) & (NC - 1);
    const int b = g >> 15;
    const size_t base = ((size_t)(b * T_ + c * CL)) * D_ + d;

    float h = CI[(b * NC + c) * D_ + d];
    #pragma unroll 8
    for (int t = 0; t < CL; ++t) {
        const size_t idx = base + (size_t)t * D_;
        const uint32_t u = EIX[idx];
        const float e  = bfbits2f(u << 16);
        const float ix = bfbits2f(u & 0xffff0000u);
        const float a  = exp2f(e);
        const float gate = sqrtf(fmaxf((1.0f - a) * (1.0f + a), 1e-6f));
        h = fmaf(a, h, gate * ix);
        OUT[idx] = h;
    }
}

// ---------------------------------------------------------------------------
extern "C" void kernel_launch(void* const* d_in, const int* in_sizes, int n_in,
                              void* d_out, int out_size, void* d_ws, size_t ws_size,
                              hipStream_t stream)
{
    (void)in_sizes; (void)n_in; (void)out_size; (void)ws_size;
    const float* X  = (const float*)d_in[0];
    const float* H0 = (const float*)d_in[1];
    const float* Wa = (const float*)d_in[2];
    const float* Ba = (const float*)d_in[3];
    const float* Wx = (const float*)d_in[4];
    const float* Bx = (const float*)d_in[5];
    const float* LL = (const float*)d_in[6];

    // d_out doubles as scratch for the bf16-converted operands (dead before K4
    // rewrites every output element):
    //   [0,64MB)    Xsw   (bf16, swizzled 32-col k-chunked)
    //   [64,66MB)   Wasw  [66,68MB) Wxsw
    char* ob = (char*)d_out;
    __bf16* Xsw  = (__bf16*)ob;
    __bf16* Wasw = (__bf16*)(ob + ((size_t)M_ * K_ * 2));
    __bf16* Wxsw = (__bf16*)(ob + ((size_t)M_ * K_ * 2) + (size_t)K_ * D_ * 2);
    float*  OUT  = (float*)d_out;
    float*  HFINAL = OUT + (size_t)M_ * D_;    // h_final after outputs

    // ws: EIX (uint32, 128MB) | P | HE | CI (1MB each)  = 131 MB
    char* ws = (char*)d_ws;
    uint32_t* EIX = (uint32_t*)ws;
    float* P  = (float*)(ws + (size_t)M_ * D_ * 4);
    float* HE = P  + (size_t)B_ * NC * D_;
    float* CI = HE + (size_t)B_ * NC * D_;

    cvt_swz<<<dim3(M_ / 2), dim3(256), 0, stream>>>(X, Xsw, M_);
    cvt_swz<<<dim3(512), dim3(256), 0, stream>>>(Wa, Wasw, 1024);
    cvt_swz<<<dim3(512), dim3(256), 0, stream>>>(Wx, Wxsw, 1024);

    rg_gemm_gate<<<dim3((M_/BM) * (D_/BN)), dim3(512), 0, stream>>>(
        Xsw, Wasw, Wxsw, Ba, Bx, LL, EIX);

    rg_scan_chunks<<<dim3(B_ * NC * D_ / 256), dim3(256), 0, stream>>>(EIX, P, HE);
    rg_combine<<<dim3(B_ * D_ / 256), dim3(256), 0, stream>>>(P, HE, H0, CI, HFINAL);
    rg_scan_final<<<dim3(B_ * NC * D_ / 256), dim3(256), 0, stream>>>(EIX, CI, OUT);
}

// Round 7
// 317.439 us; speedup vs baseline: 1.0271x; 1.0271x over previous
//
#include <hip/hip_runtime.h>
#include <cstddef>
#include <cstdint>

// Problem constants (B,T,D fixed by the reference).
#define B_ 8
#define T_ 4096
#define D_ 1024
#define M_ (B_*T_)        // 32768 rows
#define K_ 1024
#define NC 32             // scan chunks per sequence
#define CL 128            // steps per chunk

// GEMM tile config: 256x128 output tile, dual-B (r and i), BK=64, 8 waves,
// double-buffered LDS, 32x32x16 MFMA.
#define BM 256
#define BN 128
#define BK 64
#define KCHUNKS 16

typedef __bf16 bf16x8 __attribute__((ext_vector_type(8)));
typedef float  f32x16 __attribute__((ext_vector_type(16)));

__device__ __forceinline__ void gload_lds16(const __bf16* g, __bf16* l) {
    __builtin_amdgcn_global_load_lds(
        (const __attribute__((address_space(1))) void*)g,
        (__attribute__((address_space(3))) void*)l, 16, 0, 0);
}

__device__ __forceinline__ float bfbits2f(uint32_t hi16_as_low) {
    return __builtin_bit_cast(float, hi16_as_low);
}

// ---------------------------------------------------------------------------
// cvt_swz (R3 version): fp32 [rows][1024] -> bf16, 16 k-chunks of 64 cols,
// each row 128B, XOR-swizzled: byte ^= (row&7)<<4. Inverse-swizzled source so
// linear global_load_lds lands the swizzle in LDS; ds_read applies the same
// XOR (G21). Zero bank conflicts verified (R2/R3).
// ---------------------------------------------------------------------------
__global__ __launch_bounds__(256) void cvt_swz(const float* __restrict__ src,
                                               __bf16* __restrict__ dst, int rows)
{
    const int g  = blockIdx.x * 256 + threadIdx.x;   // rows*128 threads
    const int r  = g >> 7;
    const int k0 = (g & 127) << 3;                   // 8 elems per thread
    const int kc = k0 >> 6;
    const int jj = k0 & 63;
    const float4 v0 = *reinterpret_cast<const float4*>(src + (size_t)r * 1024 + k0);
    const float4 v1 = *reinterpret_cast<const float4*>(src + (size_t)r * 1024 + k0 + 4);
    bf16x8 s;
    s[0]=(__bf16)v0.x; s[1]=(__bf16)v0.y; s[2]=(__bf16)v0.z; s[3]=(__bf16)v0.w;
    s[4]=(__bf16)v1.x; s[5]=(__bf16)v1.y; s[6]=(__bf16)v1.z; s[7]=(__bf16)v1.w;
    const uint32_t inrow = (uint32_t)(r * 128 + (jj << 1)) ^ (uint32_t)((r & 7) << 4);
    const size_t byteoff = (size_t)kc * ((size_t)rows * 128) + inrow;
    *reinterpret_cast<bf16x8*>(reinterpret_cast<char*>(dst) + byteoff) = s;
}

// ---------------------------------------------------------------------------
// K1: fused dual-GEMM + slim gate epilogue. R3 structure (depth-1 dbuf,
// counted wait with full-chunk cover) but: 32x32x16 MFMA (half the MFMA
// instructions, higher ceiling), ONE barrier per chunk (stage issued after
// the barrier; closing barrier provably redundant), hoisted ds_read bases.
// zr=x@Wa^T+ba, zi=x@Wx^T+bx; r=sig(zr), i=sig(zi); e=8*r*log2(sig(lambda));
// stores packed dword {lo: bf16(e), hi: bf16(i*x)}.
// ---------------------------------------------------------------------------
__global__ __launch_bounds__(512, 1) void rg_gemm_gate(
    const float* __restrict__ Xf,
    const __bf16* __restrict__ Xsw, const __bf16* __restrict__ Wasw,
    const __bf16* __restrict__ Wxsw, const float* __restrict__ Ba,
    const float* __restrict__ Bx, const float* __restrict__ LL,
    uint32_t* __restrict__ EIX)
{
    __shared__ __bf16 Al [2][BM * BK];   // 64 KiB
    __shared__ __bf16 Brs[2][BN * BK];   // 32 KiB
    __shared__ __bf16 Bis[2][BN * BK];   // 32 KiB

    const int tid  = threadIdx.x;
    const int lane = tid & 63;
    const int w    = tid >> 6;           // 8 waves: 4M x 2N
    const int wr   = (w >> 1) * 64;
    const int wc   = (w & 1) * 64;
    const int l31  = lane & 31;
    const int lhalf = lane >> 5;

    // XCD swizzle (1024 blocks, %8==0): n-tile fastest within each XCD.
    const int bid  = blockIdx.x;
    const int wgid = (bid & 7) * 128 + (bid >> 3);
    const int n0   = (wgid & 7) << 7;    // 8 n-tiles
    const int m0   = (wgid >> 3) << 8;   // 128 m-tiles

    // Hoisted ds_read row bases + swizzle keys.
    // Frag read (32x32x16): row = l31 within 32-row frag; 16B slot =
    // (ksub*2 + lhalf) ^ (row&7). Per 16-lane group row&7 cycles 2x through
    // 8 slots -> 2 lanes/slot (free, same distribution as verified R3 reads).
    uint32_t rbA[2], rbB[2];
    uint32_t swA[2], swB[2];
    #pragma unroll
    for (int mf = 0; mf < 2; ++mf) {
        const int ra = wr + mf * 32 + l31;
        rbA[mf] = (uint32_t)(ra * 128);
        swA[mf] = (uint32_t)(ra & 7);
    }
    #pragma unroll
    for (int nf = 0; nf < 2; ++nf) {
        const int rb = wc + nf * 32 + l31;
        rbB[nf] = (uint32_t)(rb * 128);
        swB[nf] = (uint32_t)(rb & 7);
    }

    // Stage cursors: per chunk a wave issues 8 gl_lds (1 KiB each):
    // A pieces {w, w+8, w+16, w+24}, Br pieces {w, w+8}, Bi pieces {w, w+8}.
    const char* srcA  = reinterpret_cast<const char*>(Xsw)
                      + (size_t)m0 * 128 + w * 1024 + lane * 16;
    const char* srcBr = reinterpret_cast<const char*>(Wasw)
                      + (size_t)n0 * 128 + w * 1024 + lane * 16;
    const char* srcBi = reinterpret_cast<const char*>(Wxsw)
                      + (size_t)n0 * 128 + w * 1024 + lane * 16;
    const size_t strA = (size_t)M_ * 128;    // bytes per k-chunk of Xsw
    const size_t strB = (size_t)1024 * 128;  // bytes per k-chunk of W panels

    auto STAGE = [&](int buf, int kc) {
        const char* sA = srcA + (size_t)kc * strA;
        const char* sR = srcBr + (size_t)kc * strB;
        const char* sI = srcBi + (size_t)kc * strB;
        #pragma unroll
        for (int c = 0; c < 4; ++c)
            gload_lds16((const __bf16*)(sA + c * 8192), &Al[buf][(c * 8 + w) * 512]);
        #pragma unroll
        for (int c = 0; c < 2; ++c) {
            gload_lds16((const __bf16*)(sR + c * 8192), &Brs[buf][(c * 8 + w) * 512]);
            gload_lds16((const __bf16*)(sI + c * 8192), &Bis[buf][(c * 8 + w) * 512]);
        }
    };

    f32x16 accr[2][2] = {};
    f32x16 acci[2][2] = {};

    STAGE(0, 0);
    for (int kc = 0; kc < KCHUNKS; ++kc) {
        const int cur = kc & 1;
        // Drain STAGE(kc) (issued one full chunk ago -> wait is cheap),
        // publish across waves; then issue next stage into the other buffer
        // (all reads of that buffer retired before this barrier).
        asm volatile("s_waitcnt vmcnt(0)" ::: "memory");
        __builtin_amdgcn_s_barrier();
        if (kc < KCHUNKS - 1) STAGE(cur ^ 1, kc + 1);

        const char* Ab = reinterpret_cast<const char*>(&Al [cur][0]);
        const char* Rb = reinterpret_cast<const char*>(&Brs[cur][0]);
        const char* Ib = reinterpret_cast<const char*>(&Bis[cur][0]);

        #pragma unroll
        for (int ksub = 0; ksub < 4; ++ksub) {
            const uint32_t slot = (uint32_t)((ksub << 1) | lhalf);
            bf16x8 af[2], brf[2], bif[2];
            #pragma unroll
            for (int mf = 0; mf < 2; ++mf)
                af[mf] = *reinterpret_cast<const bf16x8*>(
                    Ab + rbA[mf] + ((slot ^ swA[mf]) << 4));
            #pragma unroll
            for (int nf = 0; nf < 2; ++nf) {
                brf[nf] = *reinterpret_cast<const bf16x8*>(
                    Rb + rbB[nf] + ((slot ^ swB[nf]) << 4));
                bif[nf] = *reinterpret_cast<const bf16x8*>(
                    Ib + rbB[nf] + ((slot ^ swB[nf]) << 4));
            }
            #pragma unroll
            for (int mf = 0; mf < 2; ++mf) {
                #pragma unroll
                for (int nf = 0; nf < 2; ++nf) {
                    accr[mf][nf] = __builtin_amdgcn_mfma_f32_32x32x16_bf16(
                        af[mf], brf[nf], accr[mf][nf], 0, 0, 0);
                    acci[mf][nf] = __builtin_amdgcn_mfma_f32_32x32x16_bf16(
                        af[mf], bif[nf], acci[mf][nf], 0, 0, 0);
                }
            }
        }
    }

    // ---- epilogue: 32x32 C/D layout (m74/m101): col = lane&31,
    // row = (reg&3) + 8*(reg>>2) + 4*(lane>>5), reg in [0,16). ----
    #pragma unroll
    for (int nf = 0; nf < 2; ++nf) {
        const int col = n0 + wc + nf * 32 + l31;
        const float lam = LL[col];
        const float l2s = -log2f(1.0f + __expf(-lam));  // log2(sigmoid(lambda))
        const float bav = Ba[col];
        const float bxv = Bx[col];
        #pragma unroll
        for (int mf = 0; mf < 2; ++mf) {
            const int rb0 = m0 + wr + mf * 32 + 4 * lhalf;
            #pragma unroll
            for (int reg = 0; reg < 16; ++reg) {
                const int row = rb0 + (reg & 3) + 8 * (reg >> 2);
                const float zr = accr[mf][nf][reg] + bav;
                const float zi = acci[mf][nf][reg] + bxv;
                const float rv = 1.0f / (1.0f + __expf(-zr));
                const float iv = 1.0f / (1.0f + __expf(-zi));
                const float ee = 8.0f * rv * l2s;       // log2(a)
                const size_t idx = (size_t)row * D_ + col;
                const float ixv = iv * Xf[idx];
                const uint16_t ebits  = __builtin_bit_cast(uint16_t, (__bf16)ee);
                const uint16_t ixbits = __builtin_bit_cast(uint16_t, (__bf16)ixv);
                EIX[idx] = (uint32_t)ebits | ((uint32_t)ixbits << 16);
            }
        }
    }
}

// ---------------------------------------------------------------------------
// K2: per-chunk summaries: P = prod a = 2^(sum e), hend = local scan from 0.
// ---------------------------------------------------------------------------
__global__ __launch_bounds__(256) void rg_scan_chunks(
    const uint32_t* __restrict__ EIX, float* __restrict__ P, float* __restrict__ HE)
{
    const int g = blockIdx.x * 256 + threadIdx.x;   // < B*NC*D = 262144
    const int d = g & (D_ - 1);
    const int c = (g >> 10) & (NC - 1);
    const int b = g >> 15;
    const size_t base = ((size_t)(b * T_ + c * CL)) * D_ + d;

    float h = 0.0f;
    float se = 0.0f;
    #pragma unroll 8
    for (int t = 0; t < CL; ++t) {
        const uint32_t u = EIX[base + (size_t)t * D_];
        const float e  = bfbits2f(u << 16);
        const float ix = bfbits2f(u & 0xffff0000u);
        const float a  = exp2f(e);
        const float gate = sqrtf(fmaxf((1.0f - a) * (1.0f + a), 1e-6f));
        h = fmaf(a, h, gate * ix);
        se += e;
    }
    const int sidx = (b * NC + c) * D_ + d;
    P[sidx]  = exp2f(se);
    HE[sidx] = h;
}

// ---------------------------------------------------------------------------
// K3: sequential combine over NC chunks per (b,d); seeds with h0.
// ---------------------------------------------------------------------------
__global__ __launch_bounds__(256) void rg_combine(
    const float* __restrict__ P, const float* __restrict__ HE,
    const float* __restrict__ H0, float* __restrict__ CI,
    float* __restrict__ HF)
{
    const int g = blockIdx.x * 256 + threadIdx.x;   // < B*D = 8192
    const int d = g & (D_ - 1);
    const int b = g >> 10;
    float carry = H0[g];
    #pragma unroll
    for (int c = 0; c < NC; ++c) {
        const int sidx = (b * NC + c) * D_ + d;
        CI[sidx] = carry;
        carry = fmaf(P[sidx], carry, HE[sidx]);
    }
    HF[g] = carry;
}

// ---------------------------------------------------------------------------
// K4: final intra-chunk scan with correct carry; writes h_t to OUT (write-only).
// ---------------------------------------------------------------------------
__global__ __launch_bounds__(256) void rg_scan_final(
    const uint32_t* __restrict__ EIX, const float* __restrict__ CI,
    float* __restrict__ OUT)
{
    const int g = blockIdx.x * 256 + threadIdx.x;   // < B*NC*D
    const int d = g & (D_ - 1);
    const int c = (g >> 10) & (NC - 1);
    const int b = g >> 15;
    const size_t base = ((size_t)(b * T_ + c * CL)) * D_ + d;

    float h = CI[(b * NC + c) * D_ + d];
    #pragma unroll 8
    for (int t = 0; t < CL; ++t) {
        const size_t idx = base + (size_t)t * D_;
        const uint32_t u = EIX[idx];
        const float e  = bfbits2f(u << 16);
        const float ix = bfbits2f(u & 0xffff0000u);
        const float a  = exp2f(e);
        const float gate = sqrtf(fmaxf((1.0f - a) * (1.0f + a), 1e-6f));
        h = fmaf(a, h, gate * ix);
        OUT[idx] = h;
    }
}

// ---------------------------------------------------------------------------
extern "C" void kernel_launch(void* const* d_in, const int* in_sizes, int n_in,
                              void* d_out, int out_size, void* d_ws, size_t ws_size,
                              hipStream_t stream)
{
    (void)in_sizes; (void)n_in; (void)out_size; (void)ws_size;
    const float* X  = (const float*)d_in[0];
    const float* H0 = (const float*)d_in[1];
    const float* Wa = (const float*)d_in[2];
    const float* Ba = (const float*)d_in[3];
    const float* Wx = (const float*)d_in[4];
    const float* Bx = (const float*)d_in[5];
    const float* LL = (const float*)d_in[6];

    // d_out doubles as scratch for the bf16-converted operands (dead before K4
    // rewrites every output element):
    //   [0,64MB)    Xsw   (bf16, swizzled 64-col k-chunked)
    //   [64,66MB)   Wasw  [66,68MB) Wxsw
    char* ob = (char*)d_out;
    __bf16* Xsw  = (__bf16*)ob;
    __bf16* Wasw = (__bf16*)(ob + ((size_t)M_ * K_ * 2));
    __bf16* Wxsw = (__bf16*)(ob + ((size_t)M_ * K_ * 2) + (size_t)K_ * D_ * 2);
    float*  OUT  = (float*)d_out;
    float*  HFINAL = OUT + (size_t)M_ * D_;    // h_final after outputs

    // ws: EIX (uint32, 128MB) | P | HE | CI (1MB each)  = 131 MB
    char* ws = (char*)d_ws;
    uint32_t* EIX = (uint32_t*)ws;
    float* P  = (float*)(ws + (size_t)M_ * D_ * 4);
    float* HE = P  + (size_t)B_ * NC * D_;
    float* CI = HE + (size_t)B_ * NC * D_;

    cvt_swz<<<dim3(M_ / 2), dim3(256), 0, stream>>>(X, Xsw, M_);
    cvt_swz<<<dim3(512), dim3(256), 0, stream>>>(Wa, Wasw, 1024);
    cvt_swz<<<dim3(512), dim3(256), 0, stream>>>(Wx, Wxsw, 1024);

    rg_gemm_gate<<<dim3((M_/BM) * (D_/BN)), dim3(512), 0, stream>>>(
        X, Xsw, Wasw, Wxsw, Ba, Bx, LL, EIX);

    rg_scan_chunks<<<dim3(B_ * NC * D_ / 256), dim3(256), 0, stream>>>(EIX, P, HE);
    rg_combine<<<dim3(B_ * D_ / 256), dim3(256), 0, stream>>>(P, HE, H0, CI, HFINAL);
    rg_scan_final<<<dim3(B_ * NC * D_ / 256), dim3(256), 0, stream>>>(EIX, CI, OUT);
}

// Round 8
// 288.721 us; speedup vs baseline: 1.1293x; 1.0995x over previous
//
#include <hip/hip_runtime.h>
#include <cstddef>
#include <cstdint>

// Problem constants (B,T,D fixed by the reference).
#define B_ 8
#define T_ 4096
#define D_ 1024
#define M_ (B_*T_)        // 32768 rows
#define K_ 1024
#define NC 32             // scan chunks per sequence
#define CL 128            // steps per chunk

// GEMM tile config: 256x128 output tile, dual-B (r and i), BK=64, 8 waves.
#define BM 256
#define BN 128

typedef __bf16 bf16x8 __attribute__((ext_vector_type(8)));
typedef float  f32x4  __attribute__((ext_vector_type(4)));

__device__ __forceinline__ void gload_lds16(const __bf16* g, __bf16* l) {
    __builtin_amdgcn_global_load_lds(
        (const __attribute__((address_space(1))) void*)g,
        (__attribute__((address_space(3))) void*)l, 16, 0, 0);
}

__device__ __forceinline__ float bfbits2f(uint32_t hi16_as_low) {
    return __builtin_bit_cast(float, hi16_as_low);
}

// ---------------------------------------------------------------------------
// cvt_swz: fp32 [rows][1024] -> bf16, 16 k-chunks of 64 cols, each row 128B,
// XOR-swizzled: byte ^= (row&7)<<4. Inverse-swizzled source so linear
// global_load_lds lands the swizzle in LDS; ds_read applies the same XOR
// (G21). Zero bank conflicts verified (R2/R3).
// ---------------------------------------------------------------------------
__global__ __launch_bounds__(256) void cvt_swz(const float* __restrict__ src,
                                               __bf16* __restrict__ dst, int rows)
{
    const int g  = blockIdx.x * 256 + threadIdx.x;   // rows*128 threads
    const int r  = g >> 7;
    const int k0 = (g & 127) << 3;                   // 8 elems per thread
    const int kc = k0 >> 6;
    const int jj = k0 & 63;
    const float4 v0 = *reinterpret_cast<const float4*>(src + (size_t)r * 1024 + k0);
    const float4 v1 = *reinterpret_cast<const float4*>(src + (size_t)r * 1024 + k0 + 4);
    bf16x8 s;
    s[0]=(__bf16)v0.x; s[1]=(__bf16)v0.y; s[2]=(__bf16)v0.z; s[3]=(__bf16)v0.w;
    s[4]=(__bf16)v1.x; s[5]=(__bf16)v1.y; s[6]=(__bf16)v1.z; s[7]=(__bf16)v1.w;
    const uint32_t inrow = (uint32_t)(r * 128 + (jj << 1)) ^ (uint32_t)((r & 7) << 4);
    const size_t byteoff = (size_t)kc * ((size_t)rows * 128) + inrow;
    *reinterpret_cast<bf16x8*>(reinterpret_cast<char*>(dst) + byteoff) = s;
}

// ---------------------------------------------------------------------------
// K1: fused dual-GEMM + slim gate epilogue + fused chunk summaries.
// Main loop = R3-verbatim (dbuf, counted vmcnt(8), 2 barriers/chunk — the
// empirically best schedule; R4-R7 alternatives all regressed).
// zr=x@Wa^T+ba, zi=x@Wx^T+bx; r=sig(zr), i=sig(zi); e=8*r*log2(sig(lambda));
// stores packed dword {lo: bf16(e), hi: bf16(i*x)}. Tail: block tile = 2
// chunks x 128 cols -> computes P=2^(sum e), HE=local scan directly
// (replaces the old rg_scan_chunks kernel; reads its own EIX tile from L2).
// ---------------------------------------------------------------------------
__global__ __launch_bounds__(512, 1) void rg_gemm_gate(
    const __bf16* __restrict__ Xsw, const __bf16* __restrict__ Wasw,
    const __bf16* __restrict__ Wxsw, const float* __restrict__ Ba,
    const float* __restrict__ Bx, const float* __restrict__ LL,
    uint32_t* __restrict__ EIX, float* __restrict__ Pg,
    float* __restrict__ HEg)
{
    __shared__ __bf16 Al [2][BM * 64];   // 64 KiB
    __shared__ __bf16 Brs[2][BN * 64];   // 32 KiB
    __shared__ __bf16 Bis[2][BN * 64];   // 32 KiB

    const int tid  = threadIdx.x;
    const int lane = tid & 63;
    const int w    = tid >> 6;           // 8 waves: 4M x 2N
    const int wr   = (w >> 1) * 64;
    const int wc   = (w & 1) * 64;

    // XCD swizzle (1024 blocks, %8==0): n-tile fastest within each XCD.
    const int bid  = blockIdx.x;
    const int wgid = (bid & 7) * 128 + (bid >> 3);
    const int n0   = (wgid & 7) << 7;    // 8 n-tiles
    const int m0   = (wgid >> 3) << 8;   // 128 m-tiles

    const int lrow = lane & 15;
    const int lkb  = (lane >> 4) << 4;   // byte offset of k-fragment in row

    f32x4 accr[4][4] = {};
    f32x4 acci[4][4] = {};

    // Per-wave stage = 8 global_load_lds (A:4, Br:2, Bi:2), 1 KiB each.
    auto STAGE = [&](int buf, int kc) {
        const size_t cbA = (size_t)kc * ((size_t)M_ * 64) + (size_t)m0 * 64;
        const size_t cbB = (size_t)kc * (1024 * 64) + (size_t)n0 * 64;
        #pragma unroll
        for (int c = 0; c < 4; ++c) {
            const int j = (c * 8 + w) * 512;
            gload_lds16(Xsw + cbA + j + lane * 8, &Al[buf][j]);
        }
        #pragma unroll
        for (int c = 0; c < 2; ++c) {
            const int j = (c * 8 + w) * 512;
            gload_lds16(Wasw + cbB + j + lane * 8, &Brs[buf][j]);
            gload_lds16(Wxsw + cbB + j + lane * 8, &Bis[buf][j]);
        }
    };

    STAGE(0, 0);
    for (int kc = 0; kc < 16; ++kc) {
        const int cur = kc & 1;
        if (kc < 15) {
            STAGE(cur ^ 1, kc + 1);
            asm volatile("s_waitcnt vmcnt(8)" ::: "memory");  // buf[cur] landed; next 8 in flight
        } else {
            asm volatile("s_waitcnt vmcnt(0)" ::: "memory");
        }
        __builtin_amdgcn_s_barrier();

        const char* Ab = reinterpret_cast<const char*>(Al[cur]);
        const char* Rb = reinterpret_cast<const char*>(Brs[cur]);
        const char* Ib = reinterpret_cast<const char*>(Bis[cur]);
        #pragma unroll
        for (int ks = 0; ks < 2; ++ks) {
            bf16x8 af[4], brf[4], bif[4];
            #pragma unroll
            for (int mi = 0; mi < 4; ++mi) {
                const int ra = wr + mi * 16 + lrow;
                const uint32_t bo = (uint32_t)(ra * 128 + ks * 64 + lkb)
                                  ^ (uint32_t)((ra & 7) << 4);
                af[mi] = *reinterpret_cast<const bf16x8*>(Ab + bo);
            }
            #pragma unroll
            for (int ni = 0; ni < 4; ++ni) {
                const int rb = wc + ni * 16 + lrow;
                const uint32_t bo = (uint32_t)(rb * 128 + ks * 64 + lkb)
                                  ^ (uint32_t)((rb & 7) << 4);
                brf[ni] = *reinterpret_cast<const bf16x8*>(Rb + bo);
                bif[ni] = *reinterpret_cast<const bf16x8*>(Ib + bo);
            }
            #pragma unroll
            for (int mi = 0; mi < 4; ++mi) {
                #pragma unroll
                for (int ni = 0; ni < 4; ++ni) {
                    accr[mi][ni] = __builtin_amdgcn_mfma_f32_16x16x32_bf16(
                        af[mi], brf[ni], accr[mi][ni], 0, 0, 0);
                    acci[mi][ni] = __builtin_amdgcn_mfma_f32_16x16x32_bf16(
                        af[mi], bif[ni], acci[mi][ni], 0, 0, 0);
                }
            }
        }
        __builtin_amdgcn_s_barrier();
    }

    // ---- epilogue: C/D layout col = lane&15, row = (lane>>4)*4 + j ----
    const int rbase = m0 + wr + ((lane >> 4) << 2);
    const int cbase = n0 + wc + lrow;
    #pragma unroll
    for (int ni = 0; ni < 4; ++ni) {
        const int col = cbase + ni * 16;
        const float lam = LL[col];
        const float l2s = -log2f(1.0f + __expf(-lam));  // log2(sigmoid(lambda))
        const float bav = Ba[col];
        const float bxv = Bx[col];
        const int   kcx = col >> 6;
        const uint32_t colin = (uint32_t)((col & 63) << 1);
        const char* xbase = reinterpret_cast<const char*>(Xsw)
                          + (size_t)kcx * ((size_t)M_ * 128);
        #pragma unroll
        for (int mi = 0; mi < 4; ++mi) {
            #pragma unroll
            for (int j = 0; j < 4; ++j) {
                const int row = rbase + mi * 16 + j;
                const float zr = accr[mi][ni][j] + bav;
                const float zi = acci[mi][ni][j] + bxv;
                const float rv = 1.0f / (1.0f + __expf(-zr));
                const float iv = 1.0f / (1.0f + __expf(-zi));
                const float ee = 8.0f * rv * l2s;       // log2(a)
                const uint32_t inrow = ((uint32_t)(row * 128) + colin)
                                     ^ (uint32_t)((row & 7) << 4);
                const uint16_t xb = *reinterpret_cast<const uint16_t*>(xbase + inrow);
                const float xv  = bfbits2f((uint32_t)xb << 16);
                const float ixv = iv * xv;
                const uint16_t ebits  = __builtin_bit_cast(uint16_t, (__bf16)ee);
                const uint16_t ixbits = __builtin_bit_cast(uint16_t, (__bf16)ixv);
                EIX[(size_t)row * D_ + col] = (uint32_t)ebits | ((uint32_t)ixbits << 16);
            }
        }
    }

    // ---- fused chunk summaries (replaces rg_scan_chunks) ----------------
    // Block tile = rows m0..m0+255 = 2 chunks x cols n0..n0+127. All EIX
    // stores drain (vmcnt0) then barrier: block-visible via shared L1/L2.
    asm volatile("s_waitcnt vmcnt(0)" ::: "memory");
    __syncthreads();
    float* SE = reinterpret_cast<float*>(&Al[0][0]);   // dead LDS reuse
    float* SH = SE + 512;
    {
        const int col  = tid & 127;
        const int part = tid >> 7;       // rows [part*64, part*64+64)
        const uint32_t* src = EIX + (size_t)(m0 + part * 64) * D_ + n0 + col;
        float h = 0.0f, se = 0.0f;
        #pragma unroll 4
        for (int i = 0; i < 64; ++i) {
            const uint32_t u = src[(size_t)i * D_];
            const float e  = bfbits2f(u << 16);
            const float ix = bfbits2f(u & 0xffff0000u);
            const float a  = exp2f(e);
            const float gate = sqrtf(fmaxf((1.0f - a) * (1.0f + a), 1e-6f));
            h = fmaf(a, h, gate * ix);
            se += e;
        }
        SE[tid] = se;
        SH[tid] = h;
    }
    __syncthreads();
    if (tid < 256) {
        const int chunk = tid >> 7;      // 0/1 within this tile
        const int col   = tid & 127;
        const float se0 = SE[chunk * 256 + col];
        const float h0  = SH[chunk * 256 + col];
        const float se1 = SE[chunk * 256 + 128 + col];
        const float h1  = SH[chunk * 256 + 128 + col];
        const int b     = m0 >> 12;
        const int cglob = ((m0 & 4095) >> 7) + chunk;
        const int sidx  = (b * NC + cglob) * D_ + n0 + col;
        Pg[sidx]  = exp2f(se0 + se1);
        HEg[sidx] = fmaf(exp2f(se1), h0, h1);
    }
}

// ---------------------------------------------------------------------------
// K3: sequential combine over NC chunks per (b,d); seeds with h0.
// ---------------------------------------------------------------------------
__global__ __launch_bounds__(256) void rg_combine(
    const float* __restrict__ P, const float* __restrict__ HE,
    const float* __restrict__ H0, float* __restrict__ CI,
    float* __restrict__ HF)
{
    const int g = blockIdx.x * 256 + threadIdx.x;   // < B*D = 8192
    const int d = g & (D_ - 1);
    const int b = g >> 10;
    float carry = H0[g];
    #pragma unroll
    for (int c = 0; c < NC; ++c) {
        const int sidx = (b * NC + c) * D_ + d;
        CI[sidx] = carry;
        carry = fmaf(P[sidx], carry, HE[sidx]);
    }
    HF[g] = carry;
}

// ---------------------------------------------------------------------------
// K4: final intra-chunk scan with correct carry; writes h_t to OUT (write-only).
// ---------------------------------------------------------------------------
__global__ __launch_bounds__(256) void rg_scan_final(
    const uint32_t* __restrict__ EIX, const float* __restrict__ CI,
    float* __restrict__ OUT)
{
    const int g = blockIdx.x * 256 + threadIdx.x;   // < B*NC*D
    const int d = g & (D_ - 1);
    const int c = (g >> 10) & (NC - 1);
    const int b = g >> 15;
    const size_t base = ((size_t)(b * T_ + c * CL)) * D_ + d;

    float h = CI[(b * NC + c) * D_ + d];
    #pragma unroll 8
    for (int t = 0; t < CL; ++t) {
        const size_t idx = base + (size_t)t * D_;
        const uint32_t u = EIX[idx];
        const float e  = bfbits2f(u << 16);
        const float ix = bfbits2f(u & 0xffff0000u);
        const float a  = exp2f(e);
        const float gate = sqrtf(fmaxf((1.0f - a) * (1.0f + a), 1e-6f));
        h = fmaf(a, h, gate * ix);
        OUT[idx] = h;
    }
}

// ---------------------------------------------------------------------------
extern "C" void kernel_launch(void* const* d_in, const int* in_sizes, int n_in,
                              void* d_out, int out_size, void* d_ws, size_t ws_size,
                              hipStream_t stream)
{
    (void)in_sizes; (void)n_in; (void)out_size; (void)ws_size;
    const float* X  = (const float*)d_in[0];
    const float* H0 = (const float*)d_in[1];
    const float* Wa = (const float*)d_in[2];
    const float* Ba = (const float*)d_in[3];
    const float* Wx = (const float*)d_in[4];
    const float* Bx = (const float*)d_in[5];
    const float* LL = (const float*)d_in[6];

    // d_out doubles as scratch for the bf16-converted operands (dead before K4
    // rewrites every output element):
    //   [0,64MB)    Xsw   (bf16, swizzled 64-col k-chunked)
    //   [64,66MB)   Wasw  [66,68MB) Wxsw
    char* ob = (char*)d_out;
    __bf16* Xsw  = (__bf16*)ob;
    __bf16* Wasw = (__bf16*)(ob + ((size_t)M_ * K_ * 2));
    __bf16* Wxsw = (__bf16*)(ob + ((size_t)M_ * K_ * 2) + (size_t)K_ * D_ * 2);
    float*  OUT  = (float*)d_out;
    float*  HFINAL = OUT + (size_t)M_ * D_;    // h_final after outputs

    // ws: EIX (uint32, 128MB) | P | HE | CI (1MB each)  = 131 MB
    char* ws = (char*)d_ws;
    uint32_t* EIX = (uint32_t*)ws;
    float* P  = (float*)(ws + (size_t)M_ * D_ * 4);
    float* HE = P  + (size_t)B_ * NC * D_;
    float* CI = HE + (size_t)B_ * NC * D_;

    cvt_swz<<<dim3(M_ / 2), dim3(256), 0, stream>>>(X, Xsw, M_);
    cvt_swz<<<dim3(512), dim3(256), 0, stream>>>(Wa, Wasw, 1024);
    cvt_swz<<<dim3(512), dim3(256), 0, stream>>>(Wx, Wxsw, 1024);

    rg_gemm_gate<<<dim3((M_/BM) * (D_/BN)), dim3(512), 0, stream>>>(
        Xsw, Wasw, Wxsw, Ba, Bx, LL, EIX, P, HE);

    rg_combine<<<dim3(B_ * D_ / 256), dim3(256), 0, stream>>>(P, HE, H0, CI, HFINAL);
    rg_scan_final<<<dim3(B_ * NC * D_ / 256), dim3(256), 0, stream>>>(EIX, CI, OUT);
}

// Round 9
// 270.886 us; speedup vs baseline: 1.2036x; 1.0658x over previous
//
#include <hip/hip_runtime.h>
#include <cstddef>
#include <cstdint>

// Problem constants (B,T,D fixed by the reference).
#define B_ 8
#define T_ 4096
#define D_ 1024
#define M_ (B_*T_)        // 32768 rows
#define K_ 1024
#define NC 32             // scan chunks per sequence
#define CL 128            // steps per chunk

// GEMM tile config: 256x128 output tile, dual-B (r and i), BK=64, 8 waves.
#define BM 256
#define BN 128

typedef __bf16 bf16x8 __attribute__((ext_vector_type(8)));
typedef float  f32x4  __attribute__((ext_vector_type(4)));

__device__ __forceinline__ void gload_lds16(const __bf16* g, __bf16* l) {
    __builtin_amdgcn_global_load_lds(
        (const __attribute__((address_space(1))) void*)g,
        (__attribute__((address_space(3))) void*)l, 16, 0, 0);
}

__device__ __forceinline__ float bfbits2f(uint32_t hi16_as_low) {
    return __builtin_bit_cast(float, hi16_as_low);
}

// ---------------------------------------------------------------------------
// cvt_all: one launch converting X, Wa, Wx. fp32 [rows][1024] -> bf16, 16
// k-chunks of 64 cols, 128B rows, XOR-swizzled byte ^= (row&7)<<4 (G21
// inverse-swizzled source; linear gl_lds dest; same XOR on ds_read).
// Zero bank conflicts verified (R2/R3).
// ---------------------------------------------------------------------------
__global__ __launch_bounds__(256) void cvt_all(
    const float* __restrict__ X, const float* __restrict__ Wa,
    const float* __restrict__ Wx, __bf16* __restrict__ Xsw,
    __bf16* __restrict__ Wasw, __bf16* __restrict__ Wxsw)
{
    int bb = blockIdx.x;
    const float* src; __bf16* dst; int rows;
    if (bb < M_ / 2)            { src = X;  dst = Xsw;  rows = M_;   }
    else if (bb < M_ / 2 + 512) { src = Wa; dst = Wasw; rows = 1024; bb -= M_ / 2; }
    else                        { src = Wx; dst = Wxsw; rows = 1024; bb -= M_ / 2 + 512; }

    const int g  = bb * 256 + threadIdx.x;           // rows*128 threads
    const int r  = g >> 7;
    const int k0 = (g & 127) << 3;                   // 8 elems per thread
    const int kc = k0 >> 6;
    const int jj = k0 & 63;
    const float4 v0 = *reinterpret_cast<const float4*>(src + (size_t)r * 1024 + k0);
    const float4 v1 = *reinterpret_cast<const float4*>(src + (size_t)r * 1024 + k0 + 4);
    bf16x8 s;
    s[0]=(__bf16)v0.x; s[1]=(__bf16)v0.y; s[2]=(__bf16)v0.z; s[3]=(__bf16)v0.w;
    s[4]=(__bf16)v1.x; s[5]=(__bf16)v1.y; s[6]=(__bf16)v1.z; s[7]=(__bf16)v1.w;
    const uint32_t inrow = (uint32_t)(r * 128 + (jj << 1)) ^ (uint32_t)((r & 7) << 4);
    const size_t byteoff = (size_t)kc * ((size_t)rows * 128) + inrow;
    *reinterpret_cast<bf16x8*>(reinterpret_cast<char*>(dst) + byteoff) = s;
}

// ---------------------------------------------------------------------------
// K1: fused dual-GEMM + slim gate epilogue + REGISTER-composed chunk
// summaries. Main loop = R3-verbatim (dbuf, counted vmcnt(8), 2 barriers per
// chunk — empirically best; R4-R7 schedule edits all regressed).
// Epilogue per 4-row run (mi): P_run = prod a, H_run = local scan, composed
// in dead A-LDS — NO EIX re-read (R8's fused tail was latency-bound on that).
// Replaces the separate rg_scan_chunks kernel.
// ---------------------------------------------------------------------------
__global__ __launch_bounds__(512, 1) void rg_gemm_gate(
    const __bf16* __restrict__ Xsw, const __bf16* __restrict__ Wasw,
    const __bf16* __restrict__ Wxsw, const float* __restrict__ Ba,
    const float* __restrict__ Bx, const float* __restrict__ LL,
    uint32_t* __restrict__ EIX, float* __restrict__ Pg,
    float* __restrict__ HEg)
{
    __shared__ __bf16 Al [2][BM * 64];   // 64 KiB (reused as RUNS in tail)
    __shared__ __bf16 Brs[2][BN * 64];   // 32 KiB
    __shared__ __bf16 Bis[2][BN * 64];   // 32 KiB

    const int tid  = threadIdx.x;
    const int lane = tid & 63;
    const int w    = tid >> 6;           // 8 waves: 4M x 2N
    const int wr   = (w >> 1) * 64;
    const int wc   = (w & 1) * 64;

    // XCD swizzle (1024 blocks, %8==0): n-tile fastest within each XCD.
    const int bid  = blockIdx.x;
    const int wgid = (bid & 7) * 128 + (bid >> 3);
    const int n0   = (wgid & 7) << 7;    // 8 n-tiles
    const int m0   = (wgid >> 3) << 8;   // 128 m-tiles

    const int lrow = lane & 15;
    const int lkb  = (lane >> 4) << 4;   // byte offset of k-fragment in row

    f32x4 accr[4][4] = {};
    f32x4 acci[4][4] = {};

    // Per-wave stage = 8 global_load_lds (A:4, Br:2, Bi:2), 1 KiB each.
    auto STAGE = [&](int buf, int kc) {
        const size_t cbA = (size_t)kc * ((size_t)M_ * 64) + (size_t)m0 * 64;
        const size_t cbB = (size_t)kc * (1024 * 64) + (size_t)n0 * 64;
        #pragma unroll
        for (int c = 0; c < 4; ++c) {
            const int j = (c * 8 + w) * 512;
            gload_lds16(Xsw + cbA + j + lane * 8, &Al[buf][j]);
        }
        #pragma unroll
        for (int c = 0; c < 2; ++c) {
            const int j = (c * 8 + w) * 512;
            gload_lds16(Wasw + cbB + j + lane * 8, &Brs[buf][j]);
            gload_lds16(Wxsw + cbB + j + lane * 8, &Bis[buf][j]);
        }
    };

    STAGE(0, 0);
    for (int kc = 0; kc < 16; ++kc) {
        const int cur = kc & 1;
        if (kc < 15) {
            STAGE(cur ^ 1, kc + 1);
            asm volatile("s_waitcnt vmcnt(8)" ::: "memory");  // buf[cur] landed; next 8 in flight
        } else {
            asm volatile("s_waitcnt vmcnt(0)" ::: "memory");
        }
        __builtin_amdgcn_s_barrier();

        const char* Ab = reinterpret_cast<const char*>(Al[cur]);
        const char* Rb = reinterpret_cast<const char*>(Brs[cur]);
        const char* Ib = reinterpret_cast<const char*>(Bis[cur]);
        #pragma unroll
        for (int ks = 0; ks < 2; ++ks) {
            bf16x8 af[4], brf[4], bif[4];
            #pragma unroll
            for (int mi = 0; mi < 4; ++mi) {
                const int ra = wr + mi * 16 + lrow;
                const uint32_t bo = (uint32_t)(ra * 128 + ks * 64 + lkb)
                                  ^ (uint32_t)((ra & 7) << 4);
                af[mi] = *reinterpret_cast<const bf16x8*>(Ab + bo);
            }
            #pragma unroll
            for (int ni = 0; ni < 4; ++ni) {
                const int rb = wc + ni * 16 + lrow;
                const uint32_t bo = (uint32_t)(rb * 128 + ks * 64 + lkb)
                                  ^ (uint32_t)((rb & 7) << 4);
                brf[ni] = *reinterpret_cast<const bf16x8*>(Rb + bo);
                bif[ni] = *reinterpret_cast<const bf16x8*>(Ib + bo);
            }
            #pragma unroll
            for (int mi = 0; mi < 4; ++mi) {
                #pragma unroll
                for (int ni = 0; ni < 4; ++ni) {
                    accr[mi][ni] = __builtin_amdgcn_mfma_f32_16x16x32_bf16(
                        af[mi], brf[ni], accr[mi][ni], 0, 0, 0);
                    acci[mi][ni] = __builtin_amdgcn_mfma_f32_16x16x32_bf16(
                        af[mi], bif[ni], acci[mi][ni], 0, 0, 0);
                }
            }
        }
        __builtin_amdgcn_s_barrier();
    }

    // ---- epilogue: C/D layout col = lane&15, row = (lane>>4)*4 + j.
    // Each (ni,mi) covers 4 consecutive rows -> one run summary (P,H).
    // RUNS overlay on dead Al: [2 chunks][32 runs][128 cols] float2 = 64 KiB.
    float2* RUNS = reinterpret_cast<float2*>(&Al[0][0]);
    const int g4      = lane >> 4;
    const int rbase   = m0 + wr + (g4 << 2);
    const int cbase   = n0 + wc + lrow;
    const int chunkL  = (wr >= 128) ? 1 : 0;
    const int runBase = (wr & 64) ? 16 : 0;

    #pragma unroll
    for (int ni = 0; ni < 4; ++ni) {
        const int col = cbase + ni * 16;
        const int colL = wc + ni * 16 + lrow;
        const float lam = LL[col];
        const float l2s = -log2f(1.0f + __expf(-lam));  // log2(sigmoid(lambda))
        const float bav = Ba[col];
        const float bxv = Bx[col];
        const int   kcx = col >> 6;
        const uint32_t colin = (uint32_t)((col & 63) << 1);
        const char* xbase = reinterpret_cast<const char*>(Xsw)
                          + (size_t)kcx * ((size_t)M_ * 128);
        #pragma unroll
        for (int mi = 0; mi < 4; ++mi) {
            float pr = 1.0f, hr = 0.0f;
            #pragma unroll
            for (int j = 0; j < 4; ++j) {
                const int row = rbase + mi * 16 + j;
                const float zr = accr[mi][ni][j] + bav;
                const float zi = acci[mi][ni][j] + bxv;
                const float rv = 1.0f / (1.0f + __expf(-zr));
                const float iv = 1.0f / (1.0f + __expf(-zi));
                const float ee = 8.0f * rv * l2s;       // log2(a)
                const uint32_t inrow = ((uint32_t)(row * 128) + colin)
                                     ^ (uint32_t)((row & 7) << 4);
                const uint16_t xb = *reinterpret_cast<const uint16_t*>(xbase + inrow);
                const float xv  = bfbits2f((uint32_t)xb << 16);
                const float ixv = iv * xv;
                const uint16_t ebits  = __builtin_bit_cast(uint16_t, (__bf16)ee);
                const uint16_t ixbits = __builtin_bit_cast(uint16_t, (__bf16)ixv);
                EIX[(size_t)row * D_ + col] = (uint32_t)ebits | ((uint32_t)ixbits << 16);
                // run summary (same math as the old K2, reassociated in fp32)
                const float a    = exp2f(ee);
                const float gate = sqrtf(fmaxf((1.0f - a) * (1.0f + a), 1e-6f));
                pr *= a;
                hr = fmaf(a, hr, gate * ixv);
            }
            const int runidx = runBase + mi * 4 + g4;
            RUNS[(chunkL * 32 + runidx) * 128 + colL] = float2{pr, hr};
        }
    }
    __syncthreads();
    if (tid < 256) {
        const int chunk = tid >> 7;
        const int colL  = tid & 127;
        float P = 1.0f, H = 0.0f;
        #pragma unroll 8
        for (int r = 0; r < 32; ++r) {
            const float2 ph = RUNS[(chunk * 32 + r) * 128 + colL];
            H = fmaf(ph.x, H, ph.y);
            P *= ph.x;
        }
        const int b     = m0 >> 12;
        const int cglob = ((m0 & 4095) >> 7) + chunk;
        const int sidx  = (b * NC + cglob) * D_ + n0 + colL;
        Pg[sidx]  = P;
        HEg[sidx] = H;
    }
}

// ---------------------------------------------------------------------------
// K3: sequential combine over NC chunks per (b,d); seeds with h0.
// ---------------------------------------------------------------------------
__global__ __launch_bounds__(256) void rg_combine(
    const float* __restrict__ P, const float* __restrict__ HE,
    const float* __restrict__ H0, float* __restrict__ CI,
    float* __restrict__ HF)
{
    const int g = blockIdx.x * 256 + threadIdx.x;   // < B*D = 8192
    const int d = g & (D_ - 1);
    const int b = g >> 10;
    float carry = H0[g];
    #pragma unroll
    for (int c = 0; c < NC; ++c) {
        const int sidx = (b * NC + c) * D_ + d;
        CI[sidx] = carry;
        carry = fmaf(P[sidx], carry, HE[sidx]);
    }
    HF[g] = carry;
}

// ---------------------------------------------------------------------------
// K4: final intra-chunk scan with correct carry; writes h_t to OUT (write-only).
// ---------------------------------------------------------------------------
__global__ __launch_bounds__(256) void rg_scan_final(
    const uint32_t* __restrict__ EIX, const float* __restrict__ CI,
    float* __restrict__ OUT)
{
    const int g = blockIdx.x * 256 + threadIdx.x;   // < B*NC*D
    const int d = g & (D_ - 1);
    const int c = (g >> 10) & (NC - 1);
    const int b = g >> 15;
    const size_t base = ((size_t)(b * T_ + c * CL)) * D_ + d;

    float h = CI[(b * NC + c) * D_ + d];
    #pragma unroll 8
    for (int t = 0; t < CL; ++t) {
        const size_t idx = base + (size_t)t * D_;
        const uint32_t u = EIX[idx];
        const float e  = bfbits2f(u << 16);
        const float ix = bfbits2f(u & 0xffff0000u);
        const float a  = exp2f(e);
        const float gate = sqrtf(fmaxf((1.0f - a) * (1.0f + a), 1e-6f));
        h = fmaf(a, h, gate * ix);
        OUT[idx] = h;
    }
}

// ---------------------------------------------------------------------------
extern "C" void kernel_launch(void* const* d_in, const int* in_sizes, int n_in,
                              void* d_out, int out_size, void* d_ws, size_t ws_size,
                              hipStream_t stream)
{
    (void)in_sizes; (void)n_in; (void)out_size; (void)ws_size;
    const float* X  = (const float*)d_in[0];
    const float* H0 = (const float*)d_in[1];
    const float* Wa = (const float*)d_in[2];
    const float* Ba = (const float*)d_in[3];
    const float* Wx = (const float*)d_in[4];
    const float* Bx = (const float*)d_in[5];
    const float* LL = (const float*)d_in[6];

    // d_out doubles as scratch for the bf16-converted operands (dead before K4
    // rewrites every output element):
    //   [0,64MB)    Xsw   (bf16, swizzled 64-col k-chunked)
    //   [64,66MB)   Wasw  [66,68MB) Wxsw
    char* ob = (char*)d_out;
    __bf16* Xsw  = (__bf16*)ob;
    __bf16* Wasw = (__bf16*)(ob + ((size_t)M_ * K_ * 2));
    __bf16* Wxsw = (__bf16*)(ob + ((size_t)M_ * K_ * 2) + (size_t)K_ * D_ * 2);
    float*  OUT  = (float*)d_out;
    float*  HFINAL = OUT + (size_t)M_ * D_;    // h_final after outputs

    // ws: EIX (uint32, 128MB) | P | HE | CI (1MB each)  = 131 MB
    char* ws = (char*)d_ws;
    uint32_t* EIX = (uint32_t*)ws;
    float* P  = (float*)(ws + (size_t)M_ * D_ * 4);
    float* HE = P  + (size_t)B_ * NC * D_;
    float* CI = HE + (size_t)B_ * NC * D_;

    cvt_all<<<dim3(M_ / 2 + 1024), dim3(256), 0, stream>>>(
        X, Wa, Wx, Xsw, Wasw, Wxsw);

    rg_gemm_gate<<<dim3((M_/BM) * (D_/BN)), dim3(512), 0, stream>>>(
        Xsw, Wasw, Wxsw, Ba, Bx, LL, EIX, P, HE);

    rg_combine<<<dim3(B_ * D_ / 256), dim3(256), 0, stream>>>(P, HE, H0, CI, HFINAL);
    rg_scan_final<<<dim3(B_ * NC * D_ / 256), dim3(256), 0, stream>>>(EIX, CI, OUT);
}